// Round 18
// baseline (89.659 us; speedup 1.0000x reference)
//
#include <hip/hip_runtime.h>

typedef _Float16 f16;
typedef _Float16 f16x8 __attribute__((ext_vector_type(8)));
typedef float f32x4 __attribute__((ext_vector_type(4)));

static_assert(sizeof(f16x8) == 16, "f16x8 must be 16B");

#define MFMA16x16x32F(a, b, c) __builtin_amdgcn_mfma_f32_16x16x32_f16((a), (b), (c), 0, 0, 0)

// problem constants
#define NB 2
#define NL 1024
#define ND 1024
#define NH 16
#define NHD 64
#define NP 2047
#define NBH (NB * NH)  // 32

// wave-synchronous LDS fence (wave-private LDS slices): no vmcnt drain
__device__ __forceinline__ void wave_sync_lds() {
  asm volatile("s_waitcnt lgkmcnt(0)" ::: "memory");
}

// async global->LDS, 16B per lane, wave-linear dest
__device__ __forceinline__ void gload16(const f16* g, f16* lds) {
  __builtin_amdgcn_global_load_lds((const __attribute__((address_space(1))) void*)g,
                                   (__attribute__((address_space(3))) void*)lds, 16, 0, 0);
}

// ---------------- kernel 0: fused prep — Er frag-pack + X cast + both W transposes ----------------
// blocks [0,8192): er_pack; [8192,16384): X cast; [16384,17408): W transposes.
__global__ __launch_bounds__(256) void prep_all_k(const float* __restrict__ er,
                                                  f16* __restrict__ epf,
                                                  const float* __restrict__ x,
                                                  f16* __restrict__ xf,
                                                  const float* __restrict__ Wqkv,
                                                  f16* __restrict__ WTqkv,
                                                  const float* __restrict__ Wo,
                                                  f16* __restrict__ WTo) {
  const int b = blockIdx.x;
  const int t = threadIdx.x;
  if (b < 8192) {
    const int i = b * 256 + t;  // 2^21 total
    const int e = i & 7;
    const int lane = (i >> 3) & 63;
    const int half = (i >> 9) & 1;
    const int ob = (i >> 10) & 127;
    const int h = i >> 17;
    const int g = lane >> 4, cl = lane & 15;
    const int o = ob * 16 - 1024 + cl;
    const int p = (o <= 0) ? -o : (NP - o);
    const int d = half * 32 + g * 8 + e;
    epf[i] = (f16)er[(size_t)(h * NP + p) * NHD + d];
  } else if (b < 16384) {
    const int i = (b - 8192) * 256 + t;
    xf[i] = (f16)x[i];
  } else {
    __shared__ float tile[64][68];
    const int b2 = b - 16384;           // [0,1024)
    const int bx = b2 >> 4;             // [0,64)
    const int k0 = (b2 & 15) * 64;
    const float* W;
    f16* WT;
    int N, n0;
    if (bx < 48) { W = Wqkv; WT = WTqkv; N = 3072; n0 = bx * 64; }
    else         { W = Wo;   WT = WTo;   N = 1024; n0 = (bx - 48) * 64; }
    const int rc = t & 15;
    const int rr0 = t >> 4;
#pragma unroll
    for (int i = 0; i < 4; ++i) {
      const int row = rr0 + i * 16;
      float4 v = *(const float4*)(W + (size_t)(k0 + row) * N + n0 + rc * 4);
      *(float4*)&tile[row][rc * 4] = v;
    }
    __syncthreads();
    const int n = t >> 2, kc = (t & 3) * 16;
    f16x8 h0, h1;
#pragma unroll
    for (int e = 0; e < 8; ++e) h0[e] = (f16)tile[kc + e][n];
#pragma unroll
    for (int e = 0; e < 8; ++e) h1[e] = (f16)tile[kc + 8 + e][n];
    f16* dst = WT + (size_t)(n0 + n) * ND + k0 + kc;
    *(f16x8*)dst = h0;
    *(f16x8*)(dst + 8) = h1;
  }
}

// ---------------- kernel 1: QKV projection GEMM (f16, 64x128 tile, BK=64 as 2x32 sub-tiles) ----------------
__global__ __launch_bounds__(256) void qkv_gemm_k(const f16* __restrict__ Xf,
                                                  const f16* __restrict__ WT,
                                                  const float* __restrict__ bias,
                                                  f16* __restrict__ qf,
                                                  f16* __restrict__ kp, f16* __restrict__ vp) {
  __shared__ f16 sA[2][64 * 32], sB[2][128 * 32];  // 24 KB
  const int t = threadIdx.x;
  const int lane = t & 63;
  const int w = t >> 6;
  const int cl = lane & 15;
  const int g = lane >> 4;
  const int m0 = blockIdx.y * 64;
  const int n0 = blockIdx.x * 128;

  const int arow = w * 16 + (lane >> 2);
  const int brow0 = w * 32 + (lane >> 2);
  const int scol = ((lane & 3) ^ ((lane >> 3) & 3)) * 8;  // T2 source swizzle
  const int rsw = (g ^ ((cl >> 1) & 3)) * 8;              // swizzled read col

  f32x4 acc[4][2] = {};

  for (int k0 = 0; k0 < ND; k0 += 64) {
#pragma unroll
    for (int kc = 0; kc < 2; ++kc) {
      const int kk = k0 + kc * 32;
      gload16(Xf + (size_t)(m0 + arow) * ND + kk + scol, &sA[kc][w * 512]);
      const f16* gb0 = WT + (size_t)(n0 + brow0) * ND + kk + scol;
      gload16(gb0, &sB[kc][w * 1024]);
      gload16(gb0 + (size_t)16 * ND, &sB[kc][w * 1024 + 512]);
    }
    __syncthreads();

#pragma unroll
    for (int kc = 0; kc < 2; ++kc) {
      f16x8 ah[4], bh[2];
#pragma unroll
      for (int fm = 0; fm < 4; ++fm) ah[fm] = *(const f16x8*)&sA[kc][(fm * 16 + cl) * 32 + rsw];
#pragma unroll
      for (int fn = 0; fn < 2; ++fn) bh[fn] = *(const f16x8*)&sB[kc][(w * 32 + fn * 16 + cl) * 32 + rsw];
#pragma unroll
      for (int fm = 0; fm < 4; ++fm)
#pragma unroll
        for (int fn = 0; fn < 2; ++fn)
          acc[fm][fn] = MFMA16x16x32F(ah[fm], bh[fn], acc[fm][fn]);
    }
    __syncthreads();
  }

  // epilogue: bias + scatter into attention layouts (all f16)
#pragma unroll
  for (int fm = 0; fm < 4; ++fm) {
#pragma unroll
    for (int fn = 0; fn < 2; ++fn) {
#pragma unroll
      for (int reg = 0; reg < 4; ++reg) {
        const int gm = m0 + fm * 16 + g * 4 + reg;       // token row
        const int gn = n0 + w * 32 + fn * 16 + cl;       // qkv col
        float val = acc[fm][fn][reg] + bias[gn];
        const int bb = gm >> 10, lpos = gm & 1023;
        const int sec = gn >> 10, hc = gn & 1023;
        const int hh = hc >> 6, dd = hc & 63;
        const int bh = bb * NH + hh;
        if (sec == 0) {
          qf[(size_t)(bh * NL + lpos) * NHD + dd] = (f16)val;
        } else if (sec == 1) {
          const size_t idx = ((size_t)((bh * 64 + (lpos >> 4)) * 2 + (dd >> 5))) * 512 +
                             ((((dd >> 3) & 3) << 4) + (lpos & 15)) * 8 + (dd & 7);
          kp[idx] = (f16)val;
        } else {
          const size_t idx = ((size_t)(((bh * 16 + (lpos >> 6)) * 4 + (dd >> 4)) * 2 +
                                       ((lpos >> 5) & 1))) * 512 +
                             ((((lpos >> 3) & 3) << 4) + (dd & 15)) * 8 + (lpos & 7);
          vp[idx] = (f16)val;
        }
      }
    }
  }
}

// ---------------- kernel 2: attention, v14 (v13 with 2-frag prefetch: VGPR <= 128) ----------------
__global__ __launch_bounds__(256) void attn_k(const f16* __restrict__ qf,
                                              const f16* __restrict__ kp, const f16* __restrict__ vp,
                                              const f16* __restrict__ epf,
                                              f16* __restrict__ ao) {
  __shared__ float s_lds[4][16][67];
  __shared__ float mb[4][16], lbuf[4][16], linv[16];

  const int t = threadIdx.x;
  const int w = t >> 6;
  const int lane = t & 63;
  const int cl = lane & 15;
  const int g = lane >> 4;

  const int n = blockIdx.x;
  const int xcd = n & 7, idx = n >> 3;
  const int bh = (xcd << 2) | (idx >> 6);
  const int itile = 63 - (idx & 63);
  const int i0 = itile * 16;
  const int h = bh & (NH - 1);
  const int nchunks = (itile >> 2) + 1;

  const f16* qfb = qf + (size_t)(bh * NL + i0 + cl) * NHD + g * 8;
  const f16x8 q_f0 = *(const f16x8*)qfb;
  const f16x8 q_f1 = *(const f16x8*)(qfb + 32);

  f32x4 acc_o[4] = {};
  float m_s = -3e38f, l_s = 0.0f;

  // prefetch first chunk's K tile jn=0 (2 frags = 8 VGPR; stays under the 128 cliff)
  f16x8 kpre0, kpre1;
  if (w < nchunks) {
    const f16* kb0 = kp + ((size_t)(bh * 64 + ((w * 64) >> 4)) * 2) * 512 + lane * 8;
    kpre0 = *(const f16x8*)(kb0 + 0 * 512);
    kpre1 = *(const f16x8*)(kb0 + 1 * 512);
  }

  for (int jc = w; jc < nchunks; jc += 4) {
    const int j0 = jc * 64;
    const int delta = i0 - j0;

    // ---- V fragments (contiguous 1KB streams) ----
    const f16* vbase = vp + ((size_t)(bh * 16 + (j0 >> 6)) * 8) * 512 + lane * 8;
    f16x8 vf[4][2];
#pragma unroll
    for (int t4 = 0; t4 < 4; ++t4) {
      vf[t4][0] = *(const f16x8*)(vbase + (t4 * 2 + 0) * 512);
      vf[t4][1] = *(const f16x8*)(vbase + (t4 * 2 + 1) * 512);
    }

    // ---- S = Q K^T (jn 0 from prefetch; jn 1..3 direct) ----
    const f16* kbase = kp + ((size_t)(bh * 64 + (j0 >> 4)) * 2) * 512 + lane * 8;
    f32x4 acc_s[4];
    __builtin_amdgcn_s_setprio(1);
    {
      f32x4 a = {};
      a = MFMA16x16x32F(q_f0, kpre0, a);
      a = MFMA16x16x32F(q_f1, kpre1, a);
      acc_s[0] = a;
    }
#pragma unroll
    for (int jn = 1; jn < 4; ++jn) {
      f16x8 kf0 = *(const f16x8*)(kbase + (jn * 2 + 0) * 512);
      f16x8 kf1 = *(const f16x8*)(kbase + (jn * 2 + 1) * 512);
      f32x4 a = {};
      a = MFMA16x16x32F(q_f0, kf0, a);
      a = MFMA16x16x32F(q_f1, kf1, a);
      acc_s[jn] = a;
    }

    // ---- bias: 5 Er tiles ----
    const int ob0 = (delta >> 4) + 60;
    const f16* ebase = epf + ((size_t)(h * 128 + ob0) * 2) * 512 + lane * 8;
    f32x4 acc_e[5];
#pragma unroll
    for (int tt = 0; tt < 5; ++tt) {
      f16x8 ef0 = *(const f16x8*)(ebase + (tt * 2 + 0) * 512);
      f16x8 ef1 = *(const f16x8*)(ebase + (tt * 2 + 1) * 512);
      f32x4 c = {};
      c = MFMA16x16x32F(q_f0, ef0, c);
      c = MFMA16x16x32F(q_f1, ef1, c);
      acc_e[tt] = c;
    }
    __builtin_amdgcn_s_setprio(0);

    // ---- issue next chunk's K jn=0 prefetch BEFORE the fence ----
    if (jc + 4 < nchunks) {
      const f16* kbn = kp + ((size_t)(bh * 64 + ((j0 + 256) >> 4)) * 2) * 512 + lane * 8;
      kpre0 = *(const f16x8*)(kbn + 0 * 512);
      kpre1 = *(const f16x8*)(kbn + 1 * 512);
    }

    // ---- in-register diagonal gather of E into S; spill combined to LDS ----
#pragma unroll
    for (int reg = 0; reg < 4; ++reg) {
      const int r = g * 4 + reg;
      const int src = (g << 4) | ((r - cl) & 15);
      const bool ge = (r >= cl);
#pragma unroll
      for (int jn = 0; jn < 4; ++jn) {
        float e_hi = __shfl(acc_e[4 - jn][reg], src);
        float e_lo = __shfl(acc_e[3 - jn][reg], src);
        s_lds[w][r][jn * 16 + cl] = fmaf(acc_s[jn][reg], 0.125f, ge ? e_hi : e_lo);
      }
    }
    wave_sync_lds();

    // ---- online softmax; lane (g,cl): row=cl, cols {g*8+cc} U {32+g*8+cc} ----
    float sv[16];
    float tmax = -3e38f;
#pragma unroll
    for (int cc = 0; cc < 16; ++cc) {
      const int c = (cc < 8) ? (g * 8 + cc) : (32 + g * 8 + (cc - 8));
      float v = s_lds[w][cl][c];
      if (c > delta + cl) v = -3e38f;
      sv[cc] = v;
      tmax = fmaxf(tmax, v);
    }
    tmax = fmaxf(tmax, __shfl_xor(tmax, 16));
    tmax = fmaxf(tmax, __shfl_xor(tmax, 32));
    const float m_new = fmaxf(m_s, tmax);
    const float fsc = __builtin_amdgcn_exp2f((m_s - m_new) * 1.44269504f);
    float psum = 0.0f;
    f16x8 pf0, pf1;  // P lands directly in A-frag layout — no LDS round-trip
#pragma unroll
    for (int cc = 0; cc < 16; ++cc) {
      float pv = __builtin_amdgcn_exp2f((sv[cc] - m_new) * 1.44269504f);
      psum += pv;
      if (cc < 8) pf0[cc & 7] = (f16)pv;
      else        pf1[cc & 7] = (f16)pv;
    }
    psum += __shfl_xor(psum, 16);
    psum += __shfl_xor(psum, 32);
    l_s = l_s * fsc + psum;
    m_s = m_new;

    // rescale O per row (factors via shfl), accumulate PV
    float fr[4];
#pragma unroll
    for (int reg = 0; reg < 4; ++reg) fr[reg] = __shfl(fsc, g * 4 + reg);
#pragma unroll
    for (int t4 = 0; t4 < 4; ++t4) {
#pragma unroll
      for (int reg = 0; reg < 4; ++reg) acc_o[t4][reg] *= fr[reg];
    }
    __builtin_amdgcn_s_setprio(1);
#pragma unroll
    for (int t4 = 0; t4 < 4; ++t4) {
      acc_o[t4] = MFMA16x16x32F(pf0, vf[t4][0], acc_o[t4]);
      acc_o[t4] = MFMA16x16x32F(pf1, vf[t4][1], acc_o[t4]);
    }
    __builtin_amdgcn_s_setprio(0);
  }

  // ---- flash-merge the 4 waves' partials (s_lds reused as obuf) ----
  if (lane < 16) {
    mb[w][lane] = m_s;
    lbuf[w][lane] = l_s;
  }
  __syncthreads();
  const float M = fmaxf(fmaxf(mb[0][cl], mb[1][cl]), fmaxf(mb[2][cl], mb[3][cl]));
  const float sc = __builtin_amdgcn_exp2f((m_s - M) * 1.44269504f);
  float Lt = 0.0f;
#pragma unroll
  for (int ww = 0; ww < 4; ++ww)
    Lt += lbuf[ww][cl] * __builtin_amdgcn_exp2f((mb[ww][cl] - M) * 1.44269504f);
  if (w == 0 && lane < 16) linv[lane] = 1.0f / Lt;
  float fr2[4];
#pragma unroll
  for (int reg = 0; reg < 4; ++reg) fr2[reg] = __shfl(sc, g * 4 + reg);
#pragma unroll
  for (int t4 = 0; t4 < 4; ++t4) {
#pragma unroll
    for (int reg = 0; reg < 4; ++reg)
      s_lds[w][g * 4 + reg][t4 * 16 + cl] = acc_o[t4][reg] * fr2[reg];
  }
  __syncthreads();
  const int bb = bh >> 4;
#pragma unroll
  for (int rep = 0; rep < 4; ++rep) {
    const int o_ = t + rep * 256;
    const int r = o_ >> 6, c = o_ & 63;
    float s = s_lds[0][r][c] + s_lds[1][r][c] + s_lds[2][r][c] + s_lds[3][r][c];
    ao[(size_t)(bb * NL + i0 + r) * ND + h * NHD + c] = (f16)(s * linv[r]);
  }
}

// ---------------- kernel 3: output projection (f16, 32x128 tile, BK=64, 512 blocks) ----------------
__global__ __launch_bounds__(256) void out_gemm_k(const f16* __restrict__ A,
                                                  const f16* __restrict__ WT,
                                                  const float* __restrict__ bias,
                                                  float* __restrict__ out) {
  __shared__ f16 sA[2][32 * 32], sB[2][128 * 32];  // 20 KB
  const int t = threadIdx.x;
  const int lane = t & 63, w = t >> 6;
  const int cl = lane & 15, g = lane >> 4;
  const int m0 = blockIdx.x * 32;
  const int n0 = blockIdx.y * 128;

  const int arow = w * 16 + (lane >> 2);   // valid when w < 2
  const int brow0 = w * 32 + (lane >> 2);
  const int scol = ((lane & 3) ^ ((lane >> 3) & 3)) * 8;
  const int rsw = (g ^ ((cl >> 1) & 3)) * 8;

  f32x4 acc[2][2] = {};

  for (int k0 = 0; k0 < ND; k0 += 64) {
#pragma unroll
    for (int kc = 0; kc < 2; ++kc) {
      const int kk = k0 + kc * 32;
      if (w < 2) gload16(A + (size_t)(m0 + arow) * ND + kk + scol, &sA[kc][w * 512]);
      const f16* gb0 = WT + (size_t)(n0 + brow0) * ND + kk + scol;
      gload16(gb0, &sB[kc][w * 1024]);
      gload16(gb0 + (size_t)16 * ND, &sB[kc][w * 1024 + 512]);
    }
    __syncthreads();
#pragma unroll
    for (int kc = 0; kc < 2; ++kc) {
      f16x8 ah[2], bh[2];
#pragma unroll
      for (int fm = 0; fm < 2; ++fm) ah[fm] = *(const f16x8*)&sA[kc][(fm * 16 + cl) * 32 + rsw];
#pragma unroll
      for (int fn = 0; fn < 2; ++fn) bh[fn] = *(const f16x8*)&sB[kc][(w * 32 + fn * 16 + cl) * 32 + rsw];
#pragma unroll
      for (int fm = 0; fm < 2; ++fm)
#pragma unroll
        for (int fn = 0; fn < 2; ++fn)
          acc[fm][fn] = MFMA16x16x32F(ah[fm], bh[fn], acc[fm][fn]);
    }
    __syncthreads();
  }
#pragma unroll
  for (int fm = 0; fm < 2; ++fm) {
#pragma unroll
    for (int fn = 0; fn < 2; ++fn) {
#pragma unroll
      for (int reg = 0; reg < 4; ++reg) {
        const int gm = m0 + fm * 16 + g * 4 + reg;
        const int gn = n0 + w * 32 + fn * 16 + cl;
        out[(size_t)gm * ND + gn] = acc[fm][fn][reg] + bias[gn];
      }
    }
  }
}

extern "C" void kernel_launch(void* const* d_in, const int* in_sizes, int n_in,
                              void* d_out, int out_size, void* d_ws, size_t ws_size,
                              hipStream_t stream) {
  (void)in_sizes; (void)n_in; (void)out_size; (void)ws_size;
  const float* x = (const float*)d_in[0];
  // d_in[1] = causal mask — structural (triu k=1), computed inline
  const float* Wqkv = (const float*)d_in[2];
  const float* bqkv = (const float*)d_in[3];
  const float* Wo = (const float*)d_in[4];
  const float* bo = (const float*)d_in[5];
  const float* Er = (const float*)d_in[6];

  char* ws = (char*)d_ws;
  size_t off = 0;
  auto take = [&](size_t bytes) {
    char* p = ws + off;
    off += (bytes + 255) & ~(size_t)255;
    return p;
  };
  const size_t qkN = (size_t)NBH * NL * NHD;       // 2,097,152
  const size_t xN = (size_t)NB * NL * ND;          // 2,097,152
  const size_t erpN = (size_t)NH * 128 * 2 * 512;  // 2,097,152
  f16* epf = (f16*)take(erpN * 2);
  f16* qfw = (f16*)take(qkN * 2);
  f16* kpw = (f16*)take(qkN * 2);    // K frag-packed
  f16* vpw = (f16*)take(qkN * 2);    // V frag-packed
  f16* wqkvt = (f16*)take((size_t)3 * ND * ND * 2);  // [3072][1024]
  f16* wot   = (f16*)take((size_t)ND * ND * 2);      // [1024][1024]
  f16* xf    = (f16*)take(xN * 2);                   // X f16
  f16* aow = wqkvt;  // alias: wqkvt dead after qkv_gemm, aow born in attn

  prep_all_k<<<17408, 256, 0, stream>>>(Er, epf, x, xf, Wqkv, wqkvt, Wo, wot);
  qkv_gemm_k<<<dim3(24, 32), 256, 0, stream>>>(xf, wqkvt, bqkv, qfw, kpw, vpw);
  attn_k<<<2048, 256, 0, stream>>>(qfw, kpw, vpw, epf, aow);
  out_gemm_k<<<dim3(64, 8), 256, 0, stream>>>(aow, wot, bo, (float*)d_out);
}

// Round 19
// 84.240 us; speedup vs baseline: 1.0643x; 1.0643x over previous
//
#include <hip/hip_runtime.h>

typedef _Float16 f16;
typedef _Float16 f16x8 __attribute__((ext_vector_type(8)));
typedef float f32x4 __attribute__((ext_vector_type(4)));

static_assert(sizeof(f16x8) == 16, "f16x8 must be 16B");

#define MFMA16x16x32F(a, b, c) __builtin_amdgcn_mfma_f32_16x16x32_f16((a), (b), (c), 0, 0, 0)

// problem constants
#define NB 2
#define NL 1024
#define ND 1024
#define NH 16
#define NHD 64
#define NP 2047
#define NBH (NB * NH)  // 32

// wave-synchronous LDS fence (wave-private LDS slices): no vmcnt drain
__device__ __forceinline__ void wave_sync_lds() {
  asm volatile("s_waitcnt lgkmcnt(0)" ::: "memory");
}

// async global->LDS, 16B per lane, wave-linear dest
__device__ __forceinline__ void gload16(const f16* g, f16* lds) {
  __builtin_amdgcn_global_load_lds((const __attribute__((address_space(1))) void*)g,
                                   (__attribute__((address_space(3))) void*)lds, 16, 0, 0);
}

// ---------------- kernel 0: fused prep — Er frag-pack + X cast + both W transposes ----------------
// blocks [0,8192): er_pack; [8192,16384): X cast; [16384,17408): W transposes.
__global__ __launch_bounds__(256) void prep_all_k(const float* __restrict__ er,
                                                  f16* __restrict__ epf,
                                                  const float* __restrict__ x,
                                                  f16* __restrict__ xf,
                                                  const float* __restrict__ Wqkv,
                                                  f16* __restrict__ WTqkv,
                                                  const float* __restrict__ Wo,
                                                  f16* __restrict__ WTo) {
  const int b = blockIdx.x;
  const int t = threadIdx.x;
  if (b < 8192) {
    const int i = b * 256 + t;  // 2^21 total
    const int e = i & 7;
    const int lane = (i >> 3) & 63;
    const int half = (i >> 9) & 1;
    const int ob = (i >> 10) & 127;
    const int h = i >> 17;
    const int g = lane >> 4, cl = lane & 15;
    const int o = ob * 16 - 1024 + cl;
    const int p = (o <= 0) ? -o : (NP - o);
    const int d = half * 32 + g * 8 + e;
    epf[i] = (f16)er[(size_t)(h * NP + p) * NHD + d];
  } else if (b < 16384) {
    const int i = (b - 8192) * 256 + t;
    xf[i] = (f16)x[i];
  } else {
    __shared__ float tile[64][68];
    const int b2 = b - 16384;           // [0,1024)
    const int bx = b2 >> 4;             // [0,64)
    const int k0 = (b2 & 15) * 64;
    const float* W;
    f16* WT;
    int N, n0;
    if (bx < 48) { W = Wqkv; WT = WTqkv; N = 3072; n0 = bx * 64; }
    else         { W = Wo;   WT = WTo;   N = 1024; n0 = (bx - 48) * 64; }
    const int rc = t & 15;
    const int rr0 = t >> 4;
#pragma unroll
    for (int i = 0; i < 4; ++i) {
      const int row = rr0 + i * 16;
      float4 v = *(const float4*)(W + (size_t)(k0 + row) * N + n0 + rc * 4);
      *(float4*)&tile[row][rc * 4] = v;
    }
    __syncthreads();
    const int n = t >> 2, kc = (t & 3) * 16;
    f16x8 h0, h1;
#pragma unroll
    for (int e = 0; e < 8; ++e) h0[e] = (f16)tile[kc + e][n];
#pragma unroll
    for (int e = 0; e < 8; ++e) h1[e] = (f16)tile[kc + 8 + e][n];
    f16* dst = WT + (size_t)(n0 + n) * ND + k0 + kc;
    *(f16x8*)dst = h0;
    *(f16x8*)(dst + 8) = h1;
  }
}

// ---------------- kernel 1: QKV projection GEMM (f16, 64x128 tile, BK=64 as 2x32 sub-tiles) ----------------
__global__ __launch_bounds__(256) void qkv_gemm_k(const f16* __restrict__ Xf,
                                                  const f16* __restrict__ WT,
                                                  const float* __restrict__ bias,
                                                  f16* __restrict__ qf,
                                                  f16* __restrict__ kp, f16* __restrict__ vp) {
  __shared__ f16 sA[2][64 * 32], sB[2][128 * 32];  // 24 KB
  const int t = threadIdx.x;
  const int lane = t & 63;
  const int w = t >> 6;
  const int cl = lane & 15;
  const int g = lane >> 4;
  const int m0 = blockIdx.y * 64;
  const int n0 = blockIdx.x * 128;

  const int arow = w * 16 + (lane >> 2);
  const int brow0 = w * 32 + (lane >> 2);
  const int scol = ((lane & 3) ^ ((lane >> 3) & 3)) * 8;  // T2 source swizzle
  const int rsw = (g ^ ((cl >> 1) & 3)) * 8;              // swizzled read col

  f32x4 acc[4][2] = {};

  for (int k0 = 0; k0 < ND; k0 += 64) {
#pragma unroll
    for (int kc = 0; kc < 2; ++kc) {
      const int kk = k0 + kc * 32;
      gload16(Xf + (size_t)(m0 + arow) * ND + kk + scol, &sA[kc][w * 512]);
      const f16* gb0 = WT + (size_t)(n0 + brow0) * ND + kk + scol;
      gload16(gb0, &sB[kc][w * 1024]);
      gload16(gb0 + (size_t)16 * ND, &sB[kc][w * 1024 + 512]);
    }
    __syncthreads();

#pragma unroll
    for (int kc = 0; kc < 2; ++kc) {
      f16x8 ah[4], bh[2];
#pragma unroll
      for (int fm = 0; fm < 4; ++fm) ah[fm] = *(const f16x8*)&sA[kc][(fm * 16 + cl) * 32 + rsw];
#pragma unroll
      for (int fn = 0; fn < 2; ++fn) bh[fn] = *(const f16x8*)&sB[kc][(w * 32 + fn * 16 + cl) * 32 + rsw];
#pragma unroll
      for (int fm = 0; fm < 4; ++fm)
#pragma unroll
        for (int fn = 0; fn < 2; ++fn)
          acc[fm][fn] = MFMA16x16x32F(ah[fm], bh[fn], acc[fm][fn]);
    }
    __syncthreads();
  }

  // epilogue: bias + scatter into attention layouts (all f16)
#pragma unroll
  for (int fm = 0; fm < 4; ++fm) {
#pragma unroll
    for (int fn = 0; fn < 2; ++fn) {
#pragma unroll
      for (int reg = 0; reg < 4; ++reg) {
        const int gm = m0 + fm * 16 + g * 4 + reg;       // token row
        const int gn = n0 + w * 32 + fn * 16 + cl;       // qkv col
        float val = acc[fm][fn][reg] + bias[gn];
        const int bb = gm >> 10, lpos = gm & 1023;
        const int sec = gn >> 10, hc = gn & 1023;
        const int hh = hc >> 6, dd = hc & 63;
        const int bh = bb * NH + hh;
        if (sec == 0) {
          qf[(size_t)(bh * NL + lpos) * NHD + dd] = (f16)val;
        } else if (sec == 1) {
          const size_t idx = ((size_t)((bh * 64 + (lpos >> 4)) * 2 + (dd >> 5))) * 512 +
                             ((((dd >> 3) & 3) << 4) + (lpos & 15)) * 8 + (dd & 7);
          kp[idx] = (f16)val;
        } else {
          const size_t idx = ((size_t)(((bh * 16 + (lpos >> 6)) * 4 + (dd >> 4)) * 2 +
                                       ((lpos >> 5) & 1))) * 512 +
                             ((((lpos >> 3) & 3) << 4) + (dd & 15)) * 8 + (lpos & 7);
          vp[idx] = (f16)val;
        }
      }
    }
  }
}

// ---------------- kernel 2: attention, v13 (v11 + cross-fence 4-frag K prefetch; best measured) ----------------
__global__ __launch_bounds__(256) void attn_k(const f16* __restrict__ qf,
                                              const f16* __restrict__ kp, const f16* __restrict__ vp,
                                              const f16* __restrict__ epf,
                                              f16* __restrict__ ao) {
  __shared__ float s_lds[4][16][67];
  __shared__ float mb[4][16], lbuf[4][16], linv[16];

  const int t = threadIdx.x;
  const int w = t >> 6;
  const int lane = t & 63;
  const int cl = lane & 15;
  const int g = lane >> 4;

  const int n = blockIdx.x;
  const int xcd = n & 7, idx = n >> 3;
  const int bh = (xcd << 2) | (idx >> 6);
  const int itile = 63 - (idx & 63);
  const int i0 = itile * 16;
  const int h = bh & (NH - 1);
  const int nchunks = (itile >> 2) + 1;

  const f16* qfb = qf + (size_t)(bh * NL + i0 + cl) * NHD + g * 8;
  const f16x8 q_f0 = *(const f16x8*)qfb;
  const f16x8 q_f1 = *(const f16x8*)(qfb + 32);

  f32x4 acc_o[4] = {};
  float m_s = -3e38f, l_s = 0.0f;

  // prefetch first chunk's K tiles jn=0,1 (4 frags, named regs)
  f16x8 kpre0, kpre1, kpre2, kpre3;
  if (w < nchunks) {
    const f16* kb0 = kp + ((size_t)(bh * 64 + ((w * 64) >> 4)) * 2) * 512 + lane * 8;
    kpre0 = *(const f16x8*)(kb0 + 0 * 512);
    kpre1 = *(const f16x8*)(kb0 + 1 * 512);
    kpre2 = *(const f16x8*)(kb0 + 2 * 512);
    kpre3 = *(const f16x8*)(kb0 + 3 * 512);
  }

  for (int jc = w; jc < nchunks; jc += 4) {
    const int j0 = jc * 64;
    const int delta = i0 - j0;

    // ---- V fragments (contiguous 1KB streams) ----
    const f16* vbase = vp + ((size_t)(bh * 16 + (j0 >> 6)) * 8) * 512 + lane * 8;
    f16x8 vf[4][2];
#pragma unroll
    for (int t4 = 0; t4 < 4; ++t4) {
      vf[t4][0] = *(const f16x8*)(vbase + (t4 * 2 + 0) * 512);
      vf[t4][1] = *(const f16x8*)(vbase + (t4 * 2 + 1) * 512);
    }

    // ---- S = Q K^T (jn 0,1 from prefetch; jn 2,3 direct) ----
    const f16* kbase = kp + ((size_t)(bh * 64 + (j0 >> 4)) * 2) * 512 + lane * 8;
    f32x4 acc_s[4];
    __builtin_amdgcn_s_setprio(1);
    {
      f32x4 a = {};
      a = MFMA16x16x32F(q_f0, kpre0, a);
      a = MFMA16x16x32F(q_f1, kpre1, a);
      acc_s[0] = a;
      f32x4 b = {};
      b = MFMA16x16x32F(q_f0, kpre2, b);
      b = MFMA16x16x32F(q_f1, kpre3, b);
      acc_s[1] = b;
    }
#pragma unroll
    for (int jn = 2; jn < 4; ++jn) {
      f16x8 kf0 = *(const f16x8*)(kbase + (jn * 2 + 0) * 512);
      f16x8 kf1 = *(const f16x8*)(kbase + (jn * 2 + 1) * 512);
      f32x4 a = {};
      a = MFMA16x16x32F(q_f0, kf0, a);
      a = MFMA16x16x32F(q_f1, kf1, a);
      acc_s[jn] = a;
    }

    // ---- bias: 5 Er tiles ----
    const int ob0 = (delta >> 4) + 60;
    const f16* ebase = epf + ((size_t)(h * 128 + ob0) * 2) * 512 + lane * 8;
    f32x4 acc_e[5];
#pragma unroll
    for (int tt = 0; tt < 5; ++tt) {
      f16x8 ef0 = *(const f16x8*)(ebase + (tt * 2 + 0) * 512);
      f16x8 ef1 = *(const f16x8*)(ebase + (tt * 2 + 1) * 512);
      f32x4 c = {};
      c = MFMA16x16x32F(q_f0, ef0, c);
      c = MFMA16x16x32F(q_f1, ef1, c);
      acc_e[tt] = c;
    }
    __builtin_amdgcn_s_setprio(0);

    // ---- issue next chunk's K prefetch BEFORE the fence (rides across softmax+PV) ----
    if (jc + 4 < nchunks) {
      const f16* kbn = kp + ((size_t)(bh * 64 + ((j0 + 256) >> 4)) * 2) * 512 + lane * 8;
      kpre0 = *(const f16x8*)(kbn + 0 * 512);
      kpre1 = *(const f16x8*)(kbn + 1 * 512);
      kpre2 = *(const f16x8*)(kbn + 2 * 512);
      kpre3 = *(const f16x8*)(kbn + 3 * 512);
    }

    // ---- in-register diagonal gather of E into S; spill combined to LDS ----
#pragma unroll
    for (int reg = 0; reg < 4; ++reg) {
      const int r = g * 4 + reg;
      const int src = (g << 4) | ((r - cl) & 15);
      const bool ge = (r >= cl);
#pragma unroll
      for (int jn = 0; jn < 4; ++jn) {
        float e_hi = __shfl(acc_e[4 - jn][reg], src);
        float e_lo = __shfl(acc_e[3 - jn][reg], src);
        s_lds[w][r][jn * 16 + cl] = fmaf(acc_s[jn][reg], 0.125f, ge ? e_hi : e_lo);
      }
    }
    wave_sync_lds();

    // ---- online softmax; lane (g,cl): row=cl, cols {g*8+cc} U {32+g*8+cc} ----
    float sv[16];
    float tmax = -3e38f;
#pragma unroll
    for (int cc = 0; cc < 16; ++cc) {
      const int c = (cc < 8) ? (g * 8 + cc) : (32 + g * 8 + (cc - 8));
      float v = s_lds[w][cl][c];
      if (c > delta + cl) v = -3e38f;
      sv[cc] = v;
      tmax = fmaxf(tmax, v);
    }
    tmax = fmaxf(tmax, __shfl_xor(tmax, 16));
    tmax = fmaxf(tmax, __shfl_xor(tmax, 32));
    const float m_new = fmaxf(m_s, tmax);
    const float fsc = __builtin_amdgcn_exp2f((m_s - m_new) * 1.44269504f);
    float psum = 0.0f;
    f16x8 pf0, pf1;  // P lands directly in A-frag layout — no LDS round-trip
#pragma unroll
    for (int cc = 0; cc < 16; ++cc) {
      float pv = __builtin_amdgcn_exp2f((sv[cc] - m_new) * 1.44269504f);
      psum += pv;
      if (cc < 8) pf0[cc & 7] = (f16)pv;
      else        pf1[cc & 7] = (f16)pv;
    }
    psum += __shfl_xor(psum, 16);
    psum += __shfl_xor(psum, 32);
    l_s = l_s * fsc + psum;
    m_s = m_new;

    // rescale O per row (factors via shfl), accumulate PV
    float fr[4];
#pragma unroll
    for (int reg = 0; reg < 4; ++reg) fr[reg] = __shfl(fsc, g * 4 + reg);
#pragma unroll
    for (int t4 = 0; t4 < 4; ++t4) {
#pragma unroll
      for (int reg = 0; reg < 4; ++reg) acc_o[t4][reg] *= fr[reg];
    }
    __builtin_amdgcn_s_setprio(1);
#pragma unroll
    for (int t4 = 0; t4 < 4; ++t4) {
      acc_o[t4] = MFMA16x16x32F(pf0, vf[t4][0], acc_o[t4]);
      acc_o[t4] = MFMA16x16x32F(pf1, vf[t4][1], acc_o[t4]);
    }
    __builtin_amdgcn_s_setprio(0);
  }

  // ---- flash-merge the 4 waves' partials (s_lds reused as obuf) ----
  if (lane < 16) {
    mb[w][lane] = m_s;
    lbuf[w][lane] = l_s;
  }
  __syncthreads();
  const float M = fmaxf(fmaxf(mb[0][cl], mb[1][cl]), fmaxf(mb[2][cl], mb[3][cl]));
  const float sc = __builtin_amdgcn_exp2f((m_s - M) * 1.44269504f);
  float Lt = 0.0f;
#pragma unroll
  for (int ww = 0; ww < 4; ++ww)
    Lt += lbuf[ww][cl] * __builtin_amdgcn_exp2f((mb[ww][cl] - M) * 1.44269504f);
  if (w == 0 && lane < 16) linv[lane] = 1.0f / Lt;
  float fr2[4];
#pragma unroll
  for (int reg = 0; reg < 4; ++reg) fr2[reg] = __shfl(sc, g * 4 + reg);
#pragma unroll
  for (int t4 = 0; t4 < 4; ++t4) {
#pragma unroll
    for (int reg = 0; reg < 4; ++reg)
      s_lds[w][g * 4 + reg][t4 * 16 + cl] = acc_o[t4][reg] * fr2[reg];
  }
  __syncthreads();
  const int bb = bh >> 4;
#pragma unroll
  for (int rep = 0; rep < 4; ++rep) {
    const int o_ = t + rep * 256;
    const int r = o_ >> 6, c = o_ & 63;
    float s = s_lds[0][r][c] + s_lds[1][r][c] + s_lds[2][r][c] + s_lds[3][r][c];
    ao[(size_t)(bb * NL + i0 + r) * ND + h * NHD + c] = (f16)(s * linv[r]);
  }
}

// ---------------- kernel 3: output projection (f16, 32x128 tile, BK=64, 512 blocks) ----------------
__global__ __launch_bounds__(256) void out_gemm_k(const f16* __restrict__ A,
                                                  const f16* __restrict__ WT,
                                                  const float* __restrict__ bias,
                                                  float* __restrict__ out) {
  __shared__ f16 sA[2][32 * 32], sB[2][128 * 32];  // 20 KB
  const int t = threadIdx.x;
  const int lane = t & 63, w = t >> 6;
  const int cl = lane & 15, g = lane >> 4;
  const int m0 = blockIdx.x * 32;
  const int n0 = blockIdx.y * 128;

  const int arow = w * 16 + (lane >> 2);   // valid when w < 2
  const int brow0 = w * 32 + (lane >> 2);
  const int scol = ((lane & 3) ^ ((lane >> 3) & 3)) * 8;
  const int rsw = (g ^ ((cl >> 1) & 3)) * 8;

  f32x4 acc[2][2] = {};

  for (int k0 = 0; k0 < ND; k0 += 64) {
#pragma unroll
    for (int kc = 0; kc < 2; ++kc) {
      const int kk = k0 + kc * 32;
      if (w < 2) gload16(A + (size_t)(m0 + arow) * ND + kk + scol, &sA[kc][w * 512]);
      const f16* gb0 = WT + (size_t)(n0 + brow0) * ND + kk + scol;
      gload16(gb0, &sB[kc][w * 1024]);
      gload16(gb0 + (size_t)16 * ND, &sB[kc][w * 1024 + 512]);
    }
    __syncthreads();
#pragma unroll
    for (int kc = 0; kc < 2; ++kc) {
      f16x8 ah[2], bh[2];
#pragma unroll
      for (int fm = 0; fm < 2; ++fm) ah[fm] = *(const f16x8*)&sA[kc][(fm * 16 + cl) * 32 + rsw];
#pragma unroll
      for (int fn = 0; fn < 2; ++fn) bh[fn] = *(const f16x8*)&sB[kc][(w * 32 + fn * 16 + cl) * 32 + rsw];
#pragma unroll
      for (int fm = 0; fm < 2; ++fm)
#pragma unroll
        for (int fn = 0; fn < 2; ++fn)
          acc[fm][fn] = MFMA16x16x32F(ah[fm], bh[fn], acc[fm][fn]);
    }
    __syncthreads();
  }
#pragma unroll
  for (int fm = 0; fm < 2; ++fm) {
#pragma unroll
    for (int fn = 0; fn < 2; ++fn) {
#pragma unroll
      for (int reg = 0; reg < 4; ++reg) {
        const int gm = m0 + fm * 16 + g * 4 + reg;
        const int gn = n0 + w * 32 + fn * 16 + cl;
        out[(size_t)gm * ND + gn] = acc[fm][fn][reg] + bias[gn];
      }
    }
  }
}

extern "C" void kernel_launch(void* const* d_in, const int* in_sizes, int n_in,
                              void* d_out, int out_size, void* d_ws, size_t ws_size,
                              hipStream_t stream) {
  (void)in_sizes; (void)n_in; (void)out_size; (void)ws_size;
  const float* x = (const float*)d_in[0];
  // d_in[1] = causal mask — structural (triu k=1), computed inline
  const float* Wqkv = (const float*)d_in[2];
  const float* bqkv = (const float*)d_in[3];
  const float* Wo = (const float*)d_in[4];
  const float* bo = (const float*)d_in[5];
  const float* Er = (const float*)d_in[6];

  char* ws = (char*)d_ws;
  size_t off = 0;
  auto take = [&](size_t bytes) {
    char* p = ws + off;
    off += (bytes + 255) & ~(size_t)255;
    return p;
  };
  const size_t qkN = (size_t)NBH * NL * NHD;       // 2,097,152
  const size_t xN = (size_t)NB * NL * ND;          // 2,097,152
  const size_t erpN = (size_t)NH * 128 * 2 * 512;  // 2,097,152
  f16* epf = (f16*)take(erpN * 2);
  f16* qfw = (f16*)take(qkN * 2);
  f16* kpw = (f16*)take(qkN * 2);    // K frag-packed
  f16* vpw = (f16*)take(qkN * 2);    // V frag-packed
  f16* wqkvt = (f16*)take((size_t)3 * ND * ND * 2);  // [3072][1024]
  f16* wot   = (f16*)take((size_t)ND * ND * 2);      // [1024][1024]
  f16* xf    = (f16*)take(xN * 2);                   // X f16
  f16* aow = wqkvt;  // alias: wqkvt dead after qkv_gemm, aow born in attn

  prep_all_k<<<17408, 256, 0, stream>>>(Er, epf, x, xf, Wqkv, wqkvt, Wo, wot);
  qkv_gemm_k<<<dim3(24, 32), 256, 0, stream>>>(xf, wqkvt, bqkv, qfw, kpw, vpw);
  attn_k<<<2048, 256, 0, stream>>>(qfw, kpw, vpw, epf, aow);
  out_gemm_k<<<dim3(64, 8), 256, 0, stream>>>(aow, wot, bo, (float*)d_out);
}

// Round 20
// 81.620 us; speedup vs baseline: 1.0985x; 1.0321x over previous
//
#include <hip/hip_runtime.h>

typedef _Float16 f16;
typedef _Float16 f16x8 __attribute__((ext_vector_type(8)));
typedef float f32x4 __attribute__((ext_vector_type(4)));

static_assert(sizeof(f16x8) == 16, "f16x8 must be 16B");

#define MFMA16x16x32F(a, b, c) __builtin_amdgcn_mfma_f32_16x16x32_f16((a), (b), (c), 0, 0, 0)

// problem constants
#define NB 2
#define NL 1024
#define ND 1024
#define NH 16
#define NHD 64
#define NP 2047
#define NBH (NB * NH)  // 32

// wave-synchronous LDS fence (wave-private LDS slices): no vmcnt drain
__device__ __forceinline__ void wave_sync_lds() {
  asm volatile("s_waitcnt lgkmcnt(0)" ::: "memory");
}

// async global->LDS, 16B per lane, wave-linear dest
__device__ __forceinline__ void gload16(const f16* g, f16* lds) {
  __builtin_amdgcn_global_load_lds((const __attribute__((address_space(1))) void*)g,
                                   (__attribute__((address_space(3))) void*)lds, 16, 0, 0);
}

// ---------------- kernel 0: prep — X cast + both W transposes ----------------
// blocks [0,8192): X cast; [8192,9216): W transposes.
__global__ __launch_bounds__(256) void prep_xw_k(const float* __restrict__ x,
                                                 f16* __restrict__ xf,
                                                 const float* __restrict__ Wqkv,
                                                 f16* __restrict__ WTqkv,
                                                 const float* __restrict__ Wo,
                                                 f16* __restrict__ WTo) {
  const int b = blockIdx.x;
  const int t = threadIdx.x;
  if (b < 8192) {
    const int i = b * 256 + t;
    xf[i] = (f16)x[i];
  } else {
    __shared__ float tile[64][68];
    const int b2 = b - 8192;            // [0,1024)
    const int bx = b2 >> 4;             // [0,64)
    const int k0 = (b2 & 15) * 64;
    const float* W;
    f16* WT;
    int N, n0;
    if (bx < 48) { W = Wqkv; WT = WTqkv; N = 3072; n0 = bx * 64; }
    else         { W = Wo;   WT = WTo;   N = 1024; n0 = (bx - 48) * 64; }
    const int rc = t & 15;
    const int rr0 = t >> 4;
#pragma unroll
    for (int i = 0; i < 4; ++i) {
      const int row = rr0 + i * 16;
      float4 v = *(const float4*)(W + (size_t)(k0 + row) * N + n0 + rc * 4);
      *(float4*)&tile[row][rc * 4] = v;
    }
    __syncthreads();
    const int n = t >> 2, kc = (t & 3) * 16;
    f16x8 h0, h1;
#pragma unroll
    for (int e = 0; e < 8; ++e) h0[e] = (f16)tile[kc + e][n];
#pragma unroll
    for (int e = 0; e < 8; ++e) h1[e] = (f16)tile[kc + 8 + e][n];
    f16* dst = WT + (size_t)(n0 + n) * ND + k0 + kc;
    *(f16x8*)dst = h0;
    *(f16x8*)(dst + 8) = h1;
  }
}

// ---------------- kernel 1: QKV projection GEMM + fused Er frag-pack ----------------
// blocks [0,768): GEMM (64x128 tile, BK=64, n-fast ordering — dispatched first);
// blocks [768,8960): Er frag-pack (fills idle CU slots behind the GEMM blocks).
__global__ __launch_bounds__(256) void qkv_gemm_k(const f16* __restrict__ Xf,
                                                  const f16* __restrict__ WT,
                                                  const float* __restrict__ bias,
                                                  f16* __restrict__ qf,
                                                  f16* __restrict__ kp, f16* __restrict__ vp,
                                                  const float* __restrict__ er,
                                                  f16* __restrict__ epf) {
  __shared__ f16 sA[2][64 * 32], sB[2][128 * 32];  // 24 KB
  const int blk = blockIdx.x;
  const int t = threadIdx.x;

  if (blk >= 768) {
    // ---- Er frag-pack branch ----
    const int i = (blk - 768) * 256 + t;  // 2^21 total
    const int e = i & 7;
    const int lane = (i >> 3) & 63;
    const int half = (i >> 9) & 1;
    const int ob = (i >> 10) & 127;
    const int h = i >> 17;
    const int g = lane >> 4, cl = lane & 15;
    const int o = ob * 16 - 1024 + cl;
    const int p = (o <= 0) ? -o : (NP - o);
    const int d = half * 32 + g * 8 + e;
    epf[i] = (f16)er[(size_t)(h * NP + p) * NHD + d];
    return;
  }

  const int lane = t & 63;
  const int w = t >> 6;
  const int cl = lane & 15;
  const int g = lane >> 4;
  const int m0 = (blk / 24) * 64;
  const int n0 = (blk % 24) * 128;

  const int arow = w * 16 + (lane >> 2);
  const int brow0 = w * 32 + (lane >> 2);
  const int scol = ((lane & 3) ^ ((lane >> 3) & 3)) * 8;  // T2 source swizzle
  const int rsw = (g ^ ((cl >> 1) & 3)) * 8;              // swizzled read col

  f32x4 acc[4][2] = {};

  for (int k0 = 0; k0 < ND; k0 += 64) {
#pragma unroll
    for (int kc = 0; kc < 2; ++kc) {
      const int kk = k0 + kc * 32;
      gload16(Xf + (size_t)(m0 + arow) * ND + kk + scol, &sA[kc][w * 512]);
      const f16* gb0 = WT + (size_t)(n0 + brow0) * ND + kk + scol;
      gload16(gb0, &sB[kc][w * 1024]);
      gload16(gb0 + (size_t)16 * ND, &sB[kc][w * 1024 + 512]);
    }
    __syncthreads();

#pragma unroll
    for (int kc = 0; kc < 2; ++kc) {
      f16x8 ah[4], bh[2];
#pragma unroll
      for (int fm = 0; fm < 4; ++fm) ah[fm] = *(const f16x8*)&sA[kc][(fm * 16 + cl) * 32 + rsw];
#pragma unroll
      for (int fn = 0; fn < 2; ++fn) bh[fn] = *(const f16x8*)&sB[kc][(w * 32 + fn * 16 + cl) * 32 + rsw];
#pragma unroll
      for (int fm = 0; fm < 4; ++fm)
#pragma unroll
        for (int fn = 0; fn < 2; ++fn)
          acc[fm][fn] = MFMA16x16x32F(ah[fm], bh[fn], acc[fm][fn]);
    }
    __syncthreads();
  }

  // epilogue: bias + scatter into attention layouts (all f16)
#pragma unroll
  for (int fm = 0; fm < 4; ++fm) {
#pragma unroll
    for (int fn = 0; fn < 2; ++fn) {
#pragma unroll
      for (int reg = 0; reg < 4; ++reg) {
        const int gm = m0 + fm * 16 + g * 4 + reg;       // token row
        const int gn = n0 + w * 32 + fn * 16 + cl;       // qkv col
        float val = acc[fm][fn][reg] + bias[gn];
        const int bb = gm >> 10, lpos = gm & 1023;
        const int sec = gn >> 10, hc = gn & 1023;
        const int hh = hc >> 6, dd = hc & 63;
        const int bh = bb * NH + hh;
        if (sec == 0) {
          qf[(size_t)(bh * NL + lpos) * NHD + dd] = (f16)val;
        } else if (sec == 1) {
          const size_t idx = ((size_t)((bh * 64 + (lpos >> 4)) * 2 + (dd >> 5))) * 512 +
                             ((((dd >> 3) & 3) << 4) + (lpos & 15)) * 8 + (dd & 7);
          kp[idx] = (f16)val;
        } else {
          const size_t idx = ((size_t)(((bh * 16 + (lpos >> 6)) * 4 + (dd >> 4)) * 2 +
                                       ((lpos >> 5) & 1))) * 512 +
                             ((((lpos >> 3) & 3) << 4) + (dd & 15)) * 8 + (lpos & 7);
          vp[idx] = (f16)val;
        }
      }
    }
  }
}

// ---------------- kernel 2: attention, v13 (v11 + cross-fence 4-frag K prefetch; best measured) ----------------
__global__ __launch_bounds__(256) void attn_k(const f16* __restrict__ qf,
                                              const f16* __restrict__ kp, const f16* __restrict__ vp,
                                              const f16* __restrict__ epf,
                                              f16* __restrict__ ao) {
  __shared__ float s_lds[4][16][67];
  __shared__ float mb[4][16], lbuf[4][16], linv[16];

  const int t = threadIdx.x;
  const int w = t >> 6;
  const int lane = t & 63;
  const int cl = lane & 15;
  const int g = lane >> 4;

  const int n = blockIdx.x;
  const int xcd = n & 7, idx = n >> 3;
  const int bh = (xcd << 2) | (idx >> 6);
  const int itile = 63 - (idx & 63);
  const int i0 = itile * 16;
  const int h = bh & (NH - 1);
  const int nchunks = (itile >> 2) + 1;

  const f16* qfb = qf + (size_t)(bh * NL + i0 + cl) * NHD + g * 8;
  const f16x8 q_f0 = *(const f16x8*)qfb;
  const f16x8 q_f1 = *(const f16x8*)(qfb + 32);

  f32x4 acc_o[4] = {};
  float m_s = -3e38f, l_s = 0.0f;

  // prefetch first chunk's K tiles jn=0,1 (4 frags, named regs)
  f16x8 kpre0, kpre1, kpre2, kpre3;
  if (w < nchunks) {
    const f16* kb0 = kp + ((size_t)(bh * 64 + ((w * 64) >> 4)) * 2) * 512 + lane * 8;
    kpre0 = *(const f16x8*)(kb0 + 0 * 512);
    kpre1 = *(const f16x8*)(kb0 + 1 * 512);
    kpre2 = *(const f16x8*)(kb0 + 2 * 512);
    kpre3 = *(const f16x8*)(kb0 + 3 * 512);
  }

  for (int jc = w; jc < nchunks; jc += 4) {
    const int j0 = jc * 64;
    const int delta = i0 - j0;

    // ---- V fragments (contiguous 1KB streams) ----
    const f16* vbase = vp + ((size_t)(bh * 16 + (j0 >> 6)) * 8) * 512 + lane * 8;
    f16x8 vf[4][2];
#pragma unroll
    for (int t4 = 0; t4 < 4; ++t4) {
      vf[t4][0] = *(const f16x8*)(vbase + (t4 * 2 + 0) * 512);
      vf[t4][1] = *(const f16x8*)(vbase + (t4 * 2 + 1) * 512);
    }

    // ---- S = Q K^T (jn 0,1 from prefetch; jn 2,3 direct) ----
    const f16* kbase = kp + ((size_t)(bh * 64 + (j0 >> 4)) * 2) * 512 + lane * 8;
    f32x4 acc_s[4];
    __builtin_amdgcn_s_setprio(1);
    {
      f32x4 a = {};
      a = MFMA16x16x32F(q_f0, kpre0, a);
      a = MFMA16x16x32F(q_f1, kpre1, a);
      acc_s[0] = a;
      f32x4 b = {};
      b = MFMA16x16x32F(q_f0, kpre2, b);
      b = MFMA16x16x32F(q_f1, kpre3, b);
      acc_s[1] = b;
    }
#pragma unroll
    for (int jn = 2; jn < 4; ++jn) {
      f16x8 kf0 = *(const f16x8*)(kbase + (jn * 2 + 0) * 512);
      f16x8 kf1 = *(const f16x8*)(kbase + (jn * 2 + 1) * 512);
      f32x4 a = {};
      a = MFMA16x16x32F(q_f0, kf0, a);
      a = MFMA16x16x32F(q_f1, kf1, a);
      acc_s[jn] = a;
    }

    // ---- bias: 5 Er tiles ----
    const int ob0 = (delta >> 4) + 60;
    const f16* ebase = epf + ((size_t)(h * 128 + ob0) * 2) * 512 + lane * 8;
    f32x4 acc_e[5];
#pragma unroll
    for (int tt = 0; tt < 5; ++tt) {
      f16x8 ef0 = *(const f16x8*)(ebase + (tt * 2 + 0) * 512);
      f16x8 ef1 = *(const f16x8*)(ebase + (tt * 2 + 1) * 512);
      f32x4 c = {};
      c = MFMA16x16x32F(q_f0, ef0, c);
      c = MFMA16x16x32F(q_f1, ef1, c);
      acc_e[tt] = c;
    }
    __builtin_amdgcn_s_setprio(0);

    // ---- issue next chunk's K prefetch BEFORE the fence (rides across softmax+PV) ----
    if (jc + 4 < nchunks) {
      const f16* kbn = kp + ((size_t)(bh * 64 + ((j0 + 256) >> 4)) * 2) * 512 + lane * 8;
      kpre0 = *(const f16x8*)(kbn + 0 * 512);
      kpre1 = *(const f16x8*)(kbn + 1 * 512);
      kpre2 = *(const f16x8*)(kbn + 2 * 512);
      kpre3 = *(const f16x8*)(kbn + 3 * 512);
    }

    // ---- in-register diagonal gather of E into S; spill combined to LDS ----
#pragma unroll
    for (int reg = 0; reg < 4; ++reg) {
      const int r = g * 4 + reg;
      const int src = (g << 4) | ((r - cl) & 15);
      const bool ge = (r >= cl);
#pragma unroll
      for (int jn = 0; jn < 4; ++jn) {
        float e_hi = __shfl(acc_e[4 - jn][reg], src);
        float e_lo = __shfl(acc_e[3 - jn][reg], src);
        s_lds[w][r][jn * 16 + cl] = fmaf(acc_s[jn][reg], 0.125f, ge ? e_hi : e_lo);
      }
    }
    wave_sync_lds();

    // ---- online softmax; lane (g,cl): row=cl, cols {g*8+cc} U {32+g*8+cc} ----
    float sv[16];
    float tmax = -3e38f;
#pragma unroll
    for (int cc = 0; cc < 16; ++cc) {
      const int c = (cc < 8) ? (g * 8 + cc) : (32 + g * 8 + (cc - 8));
      float v = s_lds[w][cl][c];
      if (c > delta + cl) v = -3e38f;
      sv[cc] = v;
      tmax = fmaxf(tmax, v);
    }
    tmax = fmaxf(tmax, __shfl_xor(tmax, 16));
    tmax = fmaxf(tmax, __shfl_xor(tmax, 32));
    const float m_new = fmaxf(m_s, tmax);
    const float fsc = __builtin_amdgcn_exp2f((m_s - m_new) * 1.44269504f);
    float psum = 0.0f;
    f16x8 pf0, pf1;  // P lands directly in A-frag layout — no LDS round-trip
#pragma unroll
    for (int cc = 0; cc < 16; ++cc) {
      float pv = __builtin_amdgcn_exp2f((sv[cc] - m_new) * 1.44269504f);
      psum += pv;
      if (cc < 8) pf0[cc & 7] = (f16)pv;
      else        pf1[cc & 7] = (f16)pv;
    }
    psum += __shfl_xor(psum, 16);
    psum += __shfl_xor(psum, 32);
    l_s = l_s * fsc + psum;
    m_s = m_new;

    // rescale O per row (factors via shfl), accumulate PV
    float fr[4];
#pragma unroll
    for (int reg = 0; reg < 4; ++reg) fr[reg] = __shfl(fsc, g * 4 + reg);
#pragma unroll
    for (int t4 = 0; t4 < 4; ++t4) {
#pragma unroll
      for (int reg = 0; reg < 4; ++reg) acc_o[t4][reg] *= fr[reg];
    }
    __builtin_amdgcn_s_setprio(1);
#pragma unroll
    for (int t4 = 0; t4 < 4; ++t4) {
      acc_o[t4] = MFMA16x16x32F(pf0, vf[t4][0], acc_o[t4]);
      acc_o[t4] = MFMA16x16x32F(pf1, vf[t4][1], acc_o[t4]);
    }
    __builtin_amdgcn_s_setprio(0);
  }

  // ---- flash-merge the 4 waves' partials (s_lds reused as obuf) ----
  if (lane < 16) {
    mb[w][lane] = m_s;
    lbuf[w][lane] = l_s;
  }
  __syncthreads();
  const float M = fmaxf(fmaxf(mb[0][cl], mb[1][cl]), fmaxf(mb[2][cl], mb[3][cl]));
  const float sc = __builtin_amdgcn_exp2f((m_s - M) * 1.44269504f);
  float Lt = 0.0f;
#pragma unroll
  for (int ww = 0; ww < 4; ++ww)
    Lt += lbuf[ww][cl] * __builtin_amdgcn_exp2f((mb[ww][cl] - M) * 1.44269504f);
  if (w == 0 && lane < 16) linv[lane] = 1.0f / Lt;
  float fr2[4];
#pragma unroll
  for (int reg = 0; reg < 4; ++reg) fr2[reg] = __shfl(sc, g * 4 + reg);
#pragma unroll
  for (int t4 = 0; t4 < 4; ++t4) {
#pragma unroll
    for (int reg = 0; reg < 4; ++reg)
      s_lds[w][g * 4 + reg][t4 * 16 + cl] = acc_o[t4][reg] * fr2[reg];
  }
  __syncthreads();
  const int bb = bh >> 4;
#pragma unroll
  for (int rep = 0; rep < 4; ++rep) {
    const int o_ = t + rep * 256;
    const int r = o_ >> 6, c = o_ & 63;
    float s = s_lds[0][r][c] + s_lds[1][r][c] + s_lds[2][r][c] + s_lds[3][r][c];
    ao[(size_t)(bb * NL + i0 + r) * ND + h * NHD + c] = (f16)(s * linv[r]);
  }
}

// ---------------- kernel 3: output projection (f16, 32x128 tile, BK=64, 512 blocks) ----------------
__global__ __launch_bounds__(256) void out_gemm_k(const f16* __restrict__ A,
                                                  const f16* __restrict__ WT,
                                                  const float* __restrict__ bias,
                                                  float* __restrict__ out) {
  __shared__ f16 sA[2][32 * 32], sB[2][128 * 32];  // 20 KB
  const int t = threadIdx.x;
  const int lane = t & 63, w = t >> 6;
  const int cl = lane & 15, g = lane >> 4;
  const int m0 = blockIdx.x * 32;
  const int n0 = blockIdx.y * 128;

  const int arow = w * 16 + (lane >> 2);   // valid when w < 2
  const int brow0 = w * 32 + (lane >> 2);
  const int scol = ((lane & 3) ^ ((lane >> 3) & 3)) * 8;
  const int rsw = (g ^ ((cl >> 1) & 3)) * 8;

  f32x4 acc[2][2] = {};

  for (int k0 = 0; k0 < ND; k0 += 64) {
#pragma unroll
    for (int kc = 0; kc < 2; ++kc) {
      const int kk = k0 + kc * 32;
      if (w < 2) gload16(A + (size_t)(m0 + arow) * ND + kk + scol, &sA[kc][w * 512]);
      const f16* gb0 = WT + (size_t)(n0 + brow0) * ND + kk + scol;
      gload16(gb0, &sB[kc][w * 1024]);
      gload16(gb0 + (size_t)16 * ND, &sB[kc][w * 1024 + 512]);
    }
    __syncthreads();
#pragma unroll
    for (int kc = 0; kc < 2; ++kc) {
      f16x8 ah[2], bh[2];
#pragma unroll
      for (int fm = 0; fm < 2; ++fm) ah[fm] = *(const f16x8*)&sA[kc][(fm * 16 + cl) * 32 + rsw];
#pragma unroll
      for (int fn = 0; fn < 2; ++fn) bh[fn] = *(const f16x8*)&sB[kc][(w * 32 + fn * 16 + cl) * 32 + rsw];
#pragma unroll
      for (int fm = 0; fm < 2; ++fm)
#pragma unroll
        for (int fn = 0; fn < 2; ++fn)
          acc[fm][fn] = MFMA16x16x32F(ah[fm], bh[fn], acc[fm][fn]);
    }
    __syncthreads();
  }
#pragma unroll
  for (int fm = 0; fm < 2; ++fm) {
#pragma unroll
    for (int fn = 0; fn < 2; ++fn) {
#pragma unroll
      for (int reg = 0; reg < 4; ++reg) {
        const int gm = m0 + fm * 16 + g * 4 + reg;
        const int gn = n0 + w * 32 + fn * 16 + cl;
        out[(size_t)gm * ND + gn] = acc[fm][fn][reg] + bias[gn];
      }
    }
  }
}

extern "C" void kernel_launch(void* const* d_in, const int* in_sizes, int n_in,
                              void* d_out, int out_size, void* d_ws, size_t ws_size,
                              hipStream_t stream) {
  (void)in_sizes; (void)n_in; (void)out_size; (void)ws_size;
  const float* x = (const float*)d_in[0];
  // d_in[1] = causal mask — structural (triu k=1), computed inline
  const float* Wqkv = (const float*)d_in[2];
  const float* bqkv = (const float*)d_in[3];
  const float* Wo = (const float*)d_in[4];
  const float* bo = (const float*)d_in[5];
  const float* Er = (const float*)d_in[6];

  char* ws = (char*)d_ws;
  size_t off = 0;
  auto take = [&](size_t bytes) {
    char* p = ws + off;
    off += (bytes + 255) & ~(size_t)255;
    return p;
  };
  const size_t qkN = (size_t)NBH * NL * NHD;       // 2,097,152
  const size_t xN = (size_t)NB * NL * ND;          // 2,097,152
  const size_t erpN = (size_t)NH * 128 * 2 * 512;  // 2,097,152
  f16* epf = (f16*)take(erpN * 2);
  f16* qfw = (f16*)take(qkN * 2);
  f16* kpw = (f16*)take(qkN * 2);    // K frag-packed
  f16* vpw = (f16*)take(qkN * 2);    // V frag-packed
  f16* wqkvt = (f16*)take((size_t)3 * ND * ND * 2);  // [3072][1024]
  f16* wot   = (f16*)take((size_t)ND * ND * 2);      // [1024][1024]
  f16* xf    = (f16*)take(xN * 2);                   // X f16
  f16* aow = wqkvt;  // alias: wqkvt dead after qkv_gemm, aow born in attn

  prep_xw_k<<<9216, 256, 0, stream>>>(x, xf, Wqkv, wqkvt, Wo, wot);
  qkv_gemm_k<<<8960, 256, 0, stream>>>(xf, wqkvt, bqkv, qfw, kpw, vpw, Er, epf);
  attn_k<<<2048, 256, 0, stream>>>(qfw, kpw, vpw, epf, aow);
  out_gemm_k<<<dim3(64, 8), 256, 0, stream>>>(aow, wot, bo, (float*)d_out);
}